// Round 4
// baseline (433.400 us; speedup 1.0000x reference)
//
#include <hip/hip_runtime.h>
#include <math.h>

#define B_SZ 1024
#define NMAX 21
#define NN 441            // 21*21
#define HNF 256
#define TOT_ROWS (B_SZ * NN)   // 451584
#define TILES_PER_BATCH 7      // 441 = 7*63
#define BMV 63                 // valid rows per tile (row 63 is pad)

typedef short short8 __attribute__((ext_vector_type(8)));
typedef float float4v __attribute__((ext_vector_type(4)));

__device__ __forceinline__ float softplus_f(float x) {
    return fmaxf(x, 0.f) + log1pf(expf(-fabsf(x)));
}

__device__ __forceinline__ unsigned short f2bf(float x) {
    union { float f; unsigned int u; } v; v.f = x;
    unsigned int r = v.u + 0x7FFFu + ((v.u >> 16) & 1u);   // RNE
    return (unsigned short)(r >> 16);
}

// ---------------------------------------------------------------------------
// Pack W1 into MFMA B-fragment order as bf16.
// Fragment (kstep s 0..7, nfrag f 0..15): lane l, elem j holds
// W1[s*32 + (l>>4)*8 + j][f*16 + (l&15)].  Linear idx = ((s*16+f)*64+l)*8+j.
// ---------------------------------------------------------------------------
__global__ __launch_bounds__(256) void pack_w1(const float* __restrict__ W1,
                                               short* __restrict__ B0p)
{
    int id = blockIdx.x * 256 + threadIdx.x;   // 0..65535
    int j = id & 7, l = (id >> 3) & 63, f = (id >> 9) & 15, s = id >> 13;
    int k = s * 32 + ((l >> 4) << 3) + j;
    int c = (f << 4) + (l & 15);
    B0p[id] = (short)f2bf(W1[k * HNF + c]);
}

// ---------------------------------------------------------------------------
// Kernel 1: one block per batch, loops over 7 row-tiles (64 rows, 63 valid).
// h = relu(gnn @ W1 + b1) via single bf16 MFMA product; e2 row-dots -> raw
// D/W; emb accumulated in registers across tiles (no atomics, no memset).
// ---------------------------------------------------------------------------
__global__ __launch_bounds__(256, 4) void fused_mlp_bf16(
    const float* __restrict__ gnn, const short* __restrict__ B0p,
    const float* __restrict__ b1, const float* __restrict__ W2,
    const float* __restrict__ b2,
    float* __restrict__ Dreg, float* __restrict__ Wreg, float* __restrict__ emb)
{
    __shared__ short Abf[16384];      // 32KB: frag-linear ((kk*4+m)*64+l)*8
    __shared__ float red0[4][64];
    __shared__ float red1[4][64];

    const int t = threadIdx.x;
    const int W = t >> 6, l = t & 63;
    const int batch = blockIdx.x;
    const long bbase = (long)batch * NN;

    // staging decode (per thread, constant across tiles/k)
    const int lq   = t & 63;
    const int kk_s = lq >> 3;          // 0..7
    const int fk_s = (lq & 7) >> 1;    // 0..3
    const int jh_s = lq & 1;           // 0/1
    const long maxrow = (long)TOT_ROWS - 1;

    // fragment decode
    const int frow = l & 15;
    const int fk   = l >> 4;

    // invariant epilogue weights
    const int colbase = (W << 6) + frow;
    float w20[4], w21[4], b1v[4];
    #pragma unroll
    for (int n = 0; n < 4; n++) {
        int c = colbase + (n << 4);
        b1v[n] = b1[c];
        w20[n] = W2[2 * c];
        w21[n] = W2[2 * c + 1];
    }
    const float b20 = b2[0], b21 = b2[1];

    float embp[4] = {0.f, 0.f, 0.f, 0.f};

    for (int tile = 0; tile < TILES_PER_BATCH; tile++) {
        const long row0g = bbase + (long)tile * BMV;

        // ---- stage: coalesced loads, cvt bf16, frag-linear LDS writes ----
        #pragma unroll
        for (int k = 0; k < 16; ++k) {
            int rt = (t >> 6) + (k << 2);              // row in tile
            long ar = row0g + rt;
            if (ar > maxrow) ar = maxrow;
            const float4 v = *(const float4*)(gnn + ar * HNF + ((size_t)(t & 63) << 2));
            unsigned int p0 = (unsigned)f2bf(v.x) | ((unsigned)f2bf(v.y) << 16);
            unsigned int p1 = (unsigned)f2bf(v.z) | ((unsigned)f2bf(v.w) << 16);
            int slot = (((kk_s << 2) + (rt >> 4)) << 6) + (fk_s << 4) + (rt & 15);
            uint2 pv; pv.x = p0; pv.y = p1;
            *(uint2*)((char*)Abf + slot * 16 + (jh_s << 3)) = pv;
        }
        __syncthreads();

        // ---- MFMA: 8 k-steps x 16 (4m x 4n) ----
        float4v acc[4][4];
        #pragma unroll
        for (int m = 0; m < 4; m++)
            #pragma unroll
            for (int n = 0; n < 4; n++)
                acc[m][n] = (float4v){0.f, 0.f, 0.f, 0.f};

        #pragma unroll 2
        for (int kk = 0; kk < 8; ++kk) {
            short8 bf[4], af[4];
            #pragma unroll
            for (int n = 0; n < 4; n++) {
                int nf = (W << 2) + n;
                size_t off = (size_t)((((kk << 4) + nf) << 6) | l) << 3;
                bf[n] = *(const short8*)(B0p + off);
            }
            #pragma unroll
            for (int m = 0; m < 4; m++)
                af[m] = *(const short8*)&Abf[(size_t)((((kk << 2) + m) << 6) | l) << 3];
            #pragma unroll
            for (int m = 0; m < 4; m++)
                #pragma unroll
                for (int n = 0; n < 4; n++)
                    acc[m][n] = __builtin_amdgcn_mfma_f32_16x16x32_bf16(af[m], bf[n], acc[m][n], 0, 0, 0);
        }

        // ---- epilogue: bias+relu, e2 row-dots, emb accumulation ----
        float ps0[4][4], ps1[4][4];
        #pragma unroll
        for (int m = 0; m < 4; m++)
            #pragma unroll
            for (int j = 0; j < 4; j++) { ps0[m][j] = 0.f; ps1[m][j] = 0.f; }

        #pragma unroll
        for (int m = 0; m < 4; m++)
            #pragma unroll
            for (int n = 0; n < 4; n++)
                #pragma unroll
                for (int j = 0; j < 4; j++) {
                    float h = fmaxf(acc[m][n][j] + b1v[n], 0.f);
                    ps0[m][j] += h * w20[n];
                    ps1[m][j] += h * w21[n];
                    int row = (m << 4) + (fk << 2) + j;
                    if (row < BMV) embp[n] += h;
                }

        #pragma unroll
        for (int off = 1; off < 16; off <<= 1)
            #pragma unroll
            for (int m = 0; m < 4; m++)
                #pragma unroll
                for (int j = 0; j < 4; j++) {
                    ps0[m][j] += __shfl_xor(ps0[m][j], off);
                    ps1[m][j] += __shfl_xor(ps1[m][j], off);
                }
        if (frow == 0) {
            #pragma unroll
            for (int m = 0; m < 4; m++)
                #pragma unroll
                for (int j = 0; j < 4; j++) {
                    int row = (m << 4) + (fk << 2) + j;
                    red0[W][row] = ps0[m][j];
                    red1[W][row] = ps1[m][j];
                }
        }
        __syncthreads();
        if (t < BMV) {
            float v0 = red0[0][t] + red0[1][t] + red0[2][t] + red0[3][t] + b20;
            float v1 = red1[0][t] + red1[1][t] + red1[2][t] + red1[3][t] + b21;
            Dreg[row0g + t] = v0;    // raw e2 ch0 (symmetrized in recon)
            Wreg[row0g + t] = v1;
        }
        // next tile's staging happens after every thread passed the sync above
    }

    // ---- emb final reduce + direct write (block owns the batch) ----
    #pragma unroll
    for (int n = 0; n < 4; n++) {
        embp[n] += __shfl_xor(embp[n], 16);
        embp[n] += __shfl_xor(embp[n], 32);
    }
    if (l < 16) {
        #pragma unroll
        for (int n = 0; n < 4; n++)
            emb[(size_t)batch * 256 + (W << 6) + (n << 4) + l] = embp[n];
    }
}

// ---------------------------------------------------------------------------
// Kernel 2: fused symmetrize+softplus (writes D/W outputs) + register MDS
// recon. 1 block = 1 wave = 1 batch; lane i<21 owns row i.
// ---------------------------------------------------------------------------
__global__ __launch_bounds__(64) void symrecon_kernel(
    float* __restrict__ Dreg, float* __restrict__ Wreg,
    const float* __restrict__ un, const float* __restrict__ xn,
    float* __restrict__ Xo)
{
    const int b = blockIdx.x, l = threadIdx.x;
    __shared__ float R0[NN], R1[NN];

    float* Db = Dreg + (size_t)b * NN;
    float* Wb = Wreg + (size_t)b * NN;
    for (int idx = l; idx < NN; idx += 64) { R0[idx] = Db[idx]; R1[idx] = Wb[idx]; }
    __syncthreads();

    const bool act = (l < NMAX);
    const int li = act ? l : 0;
    float Drow[NMAX], Wrow[NMAX];
    float rs = 0.f;
    #pragma unroll
    for (int q = 0; q < NMAX; q++) {
        float rd = R0[li * NMAX + q] + R0[q * NMAX + li];
        float rw = R1[li * NMAX + q] + R1[q * NMAX + li];
        float d = (q == li) ? 0.f : softplus_f(rd);
        float wv = softplus_f(rw);
        Drow[q] = act ? d : 0.f;
        Wrow[q] = act ? wv : 0.f;
        rs += Drow[q];
    }
    // write symmetrized outputs
    if (act) {
        #pragma unroll
        for (int q = 0; q < NMAX; q++) {
            Db[l * NMAX + q] = Drow[q];
            Wb[l * NMAX + q] = Wrow[q];
        }
    }

    // double-centering -> A rows in registers
    float tot = rs;
    #pragma unroll
    for (int m = 1; m < 64; m <<= 1) tot += __shfl_xor(tot, m);
    const float mean = tot * (1.f / (float)NN);
    const float rsn = rs * (1.f / (float)NMAX);
    float Arow[NMAX];
    #pragma unroll
    for (int q = 0; q < NMAX; q++) {
        float rsq = __shfl(rsn, q);
        float v = -0.5f * (Drow[q] - rsn - rsq + mean);
        Arow[q] = act ? v : 0.f;
    }

    // deflated power iteration: k=3 eigvecs, 10 steps each
    float xr[3] = {0.f, 0.f, 0.f};
    #pragma unroll
    for (int e = 0; e < 3; e++) {
        float u = act ? un[(size_t)b * 63 + e * NMAX + l] : 0.f;
        for (int s = 0; s < 10; s++) {
            float n2 = u * u;
            #pragma unroll
            for (int m = 1; m < 64; m <<= 1) n2 += __shfl_xor(n2, m);
            u *= 1.f / fmaxf(sqrtf(n2), 1e-3f);
            float a = 0.f;
            #pragma unroll
            for (int q = 0; q < NMAX; q++) a = fmaf(Arow[q], __shfl(u, q), a);
            u = act ? a : 0.f;
        }
        float e2 = u * u;
        #pragma unroll
        for (int m = 1; m < 64; m <<= 1) e2 += __shfl_xor(e2, m);
        u *= 1.f / sqrtf(sqrtf(e2 + 0.01f));
        xr[e] = u;
        #pragma unroll
        for (int q = 0; q < NMAX; q++) Arow[q] = fmaf(-u, __shfl(u, q), Arow[q]);
    }
    float x = xr[0], y = xr[1], z = xr[2];
    if (act) {
        x += xn[(size_t)b * 63 + l * 3 + 0];
        y += xn[(size_t)b * 63 + l * 3 + 1];
        z += xn[(size_t)b * 63 + l * 3 + 2];
    }

    // 100 clipped gradient-descent steps (registers + shuffles only)
    for (int tstep = 0; tstep < 100; tstep++) {
        float gx = 0.f, gy = 0.f, gz = 0.f;
        #pragma unroll
        for (int q = 0; q < NMAX; q++) {
            float dx = x - __shfl(x, q);
            float dy = y - __shfl(y, q);
            float dz = z - __shfl(z, q);
            float s = fmaf(dx, dx, fmaf(dy, dy, fmaf(dz, dz, 0.01f)));
            float cm = Wrow[q] * (Drow[q] - s);
            gx = fmaf(cm, dx, gx);
            gy = fmaf(cm, dy, gy);
            gz = fmaf(cm, dz, gz);
        }
        float d0 = 0.8f * gx, d1 = 0.8f * gy, d2 = 0.8f * gz;
        float speed = sqrtf(fmaf(d0, d0, fmaf(d1, d1, fmaf(d2, d2, 1e-3f))));
        float alpha = 0.1f + 4.9f * (100.f - (float)tstep) * 0.01f;
        float scale = alpha * tanhf(speed / alpha) / speed;
        x = fmaf(d0, scale, x);
        y = fmaf(d1, scale, y);
        z = fmaf(d2, scale, z);
    }
    if (act) {
        Xo[(size_t)b * 63 + l * 3 + 0] = x;
        Xo[(size_t)b * 63 + l * 3 + 1] = y;
        Xo[(size_t)b * 63 + l * 3 + 2] = z;
    }
}

// ---------------------------------------------------------------------------
extern "C" void kernel_launch(void* const* d_in, const int* in_sizes, int n_in,
                              void* d_out, int out_size, void* d_ws, size_t ws_size,
                              hipStream_t stream) {
    const float* gnn = (const float*)d_in[0];
    const float* W1  = (const float*)d_in[1];
    const float* b1  = (const float*)d_in[2];
    const float* W2  = (const float*)d_in[3];
    const float* b2  = (const float*)d_in[4];
    const float* un  = (const float*)d_in[5];
    const float* xn  = (const float*)d_in[6];

    float* out  = (float*)d_out;
    float* Dreg = out;                                  // [1024*441]
    float* Wreg = out + (size_t)TOT_ROWS;               // [1024*441]
    float* emb  = out + (size_t)2 * TOT_ROWS;           // [1024*256]
    float* Xo   = out + (size_t)2 * TOT_ROWS + B_SZ*256;// [1024*63]

    short* B0p = (short*)d_ws;                          // 65536 bf16 (128KB)

    pack_w1<<<dim3(256), dim3(256), 0, stream>>>(W1, B0p);

    fused_mlp_bf16<<<dim3(B_SZ), dim3(256), 0, stream>>>(
        gnn, B0p, b1, W2, b2, Dreg, Wreg, emb);

    symrecon_kernel<<<dim3(B_SZ), dim3(64), 0, stream>>>(Dreg, Wreg, un, xn, Xo);
}

// Round 5
// 316.223 us; speedup vs baseline: 1.3706x; 1.3706x over previous
//
#include <hip/hip_runtime.h>
#include <hip/hip_bf16.h>
#include <math.h>

#define B_SZ 1024
#define NMAX 21
#define NN 441            // 21*21
#define HNF 256
#define TOT_ROWS (B_SZ * NN)   // 451584
#define TILES_PER_BATCH 7      // 441 = 7*63
#define BMV 63                 // valid rows per tile (row 63 is pad)

typedef short short8 __attribute__((ext_vector_type(8)));
typedef float float4v __attribute__((ext_vector_type(4)));

__device__ __forceinline__ float softplus_f(float x) {
    return fmaxf(x, 0.f) + log1pf(expf(-fabsf(x)));
}

__device__ __forceinline__ unsigned short f2bf(float x) {
    union { float f; unsigned int u; } v; v.f = x;
    unsigned int r = v.u + 0x7FFFu + ((v.u >> 16) & 1u);   // RNE
    return (unsigned short)(r >> 16);
}

// hardware packed fp32->bf16 (v_cvt_pk_bf16_f32), RNE
__device__ __forceinline__ unsigned pk_bf16(float lo, float hi) {
    __hip_bfloat162 h = __float22bfloat162_rn(float2{lo, hi});
    return *reinterpret_cast<unsigned*>(&h);
}

// ---------------------------------------------------------------------------
// Pack W1 into MFMA B-fragment order as bf16.
// Fragment (kstep s 0..7, nfrag f 0..15): lane l, elem j holds
// W1[s*32 + (l>>4)*8 + j][f*16 + (l&15)].  Linear idx = ((s*16+f)*64+l)*8+j.
// ---------------------------------------------------------------------------
__global__ __launch_bounds__(256) void pack_w1(const float* __restrict__ W1,
                                               short* __restrict__ B0p)
{
    int id = blockIdx.x * 256 + threadIdx.x;   // 0..65535
    int j = id & 7, l = (id >> 3) & 63, f = (id >> 9) & 15, s = id >> 13;
    int k = s * 32 + ((l >> 4) << 3) + j;
    int c = (f << 4) + (l & 15);
    B0p[id] = (short)f2bf(W1[k * HNF + c]);
}

// ---------------------------------------------------------------------------
// Kernel 1: 7168 independent blocks (one 64x256 output tile each, 63 valid
// rows). Prologue loads the whole A tile to registers, converts to bf16
// (v_cvt_pk_bf16_f32), writes fragment-linear LDS; ONE barrier; barrier-free
// 8-kstep MFMA loop (B frags from L2-resident packed W1). Fused epilogue:
// bias+relu, e2 row-dots -> raw D/W, emb partials via atomics.
// ---------------------------------------------------------------------------
__global__ __launch_bounds__(256, 4) void fused_mlp_bf16(
    const float* __restrict__ gnn, const short* __restrict__ B0p,
    const float* __restrict__ b1, const float* __restrict__ W2,
    const float* __restrict__ b2,
    float* __restrict__ Dreg, float* __restrict__ Wreg, float* __restrict__ emb)
{
    __shared__ short Abf[16384];      // 32KB frag-linear: ((kk*4+m)*64+l)*8
    __shared__ float red0[4][64];
    __shared__ float red1[4][64];

    const int t = threadIdx.x;
    const int w = t >> 6, l = t & 63;
    const int batch = blockIdx.x / TILES_PER_BATCH;
    const int tile  = blockIdx.x % TILES_PER_BATCH;
    const long row0 = (long)batch * NN + (long)tile * BMV;

    // staging mapping: thread -> (row sr, col-group skq of 8 within each k32)
    const int sr  = t >> 2;      // 0..63
    const int skq = t & 3;       // 0..3
    long arow = row0 + sr;
    if (arow >= (long)TOT_ROWS) arow = TOT_ROWS - 1;   // pad row of last block
    const float* asrc = gnn + arow * HNF + (skq << 3);

    // fragment decode for compute
    const int frow = l & 15;
    const int fk   = l >> 4;

    // ---- prologue: load whole 64x256 A tile ----
    float4 fr[16];
    #pragma unroll
    for (int kk = 0; kk < 8; kk++) {
        fr[2*kk]     = *(const float4*)(asrc + kk * 32);
        fr[2*kk + 1] = *(const float4*)(asrc + kk * 32 + 4);
    }
    // convert fp32 -> bf16, write fragment-linear LDS
    const int wbase = (skq << 4) | (sr & 15);     // lane slot this thread fills
    const int wm    = sr >> 4;                    // m-frag of this row
    #pragma unroll
    for (int kk = 0; kk < 8; kk++) {
        uint4 pv;
        pv.x = pk_bf16(fr[2*kk].x,   fr[2*kk].y);
        pv.y = pk_bf16(fr[2*kk].z,   fr[2*kk].w);
        pv.z = pk_bf16(fr[2*kk+1].x, fr[2*kk+1].y);
        pv.w = pk_bf16(fr[2*kk+1].z, fr[2*kk+1].w);
        int base = (((kk << 2) + wm) << 6 | wbase) << 3;   // in shorts, 16B-aligned
        *(uint4*)(Abf + base) = pv;
    }
    __syncthreads();

    // ---- barrier-free MFMA loop: 8 k-steps x (4m x 4n) ----
    float4v acc[4][4];
    #pragma unroll
    for (int m = 0; m < 4; m++)
        #pragma unroll
        for (int n = 0; n < 4; n++)
            acc[m][n] = (float4v){0.f, 0.f, 0.f, 0.f};

    #pragma unroll 2
    for (int kk = 0; kk < 8; ++kk) {
        short8 bf[4], af[4];
        #pragma unroll
        for (int n = 0; n < 4; n++) {
            int nf = (w << 2) + n;
            size_t off = (size_t)((((kk << 4) + nf) << 6) | l) << 3;
            bf[n] = *(const short8*)(B0p + off);
        }
        #pragma unroll
        for (int m = 0; m < 4; m++)
            af[m] = *(const short8*)(Abf + ((((kk << 2) + m) << 6) | l) * 8);
        #pragma unroll
        for (int m = 0; m < 4; m++)
            #pragma unroll
            for (int n = 0; n < 4; n++)
                acc[m][n] = __builtin_amdgcn_mfma_f32_16x16x32_bf16(af[m], bf[n], acc[m][n], 0, 0, 0);
    }

    // ---- epilogue: bias+relu, e2 row-dots, emb partials ----
    // C frag layout: col = w*64 + n*16 + (l&15), row = m*16 + (l>>4)*4 + j
    const int colbase = (w << 6) + frow;
    float w20[4], w21[4], b1v[4];
    #pragma unroll
    for (int n = 0; n < 4; n++) {
        int c = colbase + (n << 4);
        b1v[n] = b1[c];
        w20[n] = W2[2 * c];
        w21[n] = W2[2 * c + 1];
    }
    float ps0[4][4], ps1[4][4], embp[4] = {0.f, 0.f, 0.f, 0.f};
    #pragma unroll
    for (int m = 0; m < 4; m++)
        #pragma unroll
        for (int j = 0; j < 4; j++) { ps0[m][j] = 0.f; ps1[m][j] = 0.f; }

    #pragma unroll
    for (int m = 0; m < 4; m++)
        #pragma unroll
        for (int n = 0; n < 4; n++)
            #pragma unroll
            for (int j = 0; j < 4; j++) {
                float h = fmaxf(acc[m][n][j] + b1v[n], 0.f);
                ps0[m][j] += h * w20[n];
                ps1[m][j] += h * w21[n];
                int row = (m << 4) + (fk << 2) + j;
                if (row < BMV) embp[n] += h;     // exclude pad row
            }

    #pragma unroll
    for (int off = 1; off < 16; off <<= 1)
        #pragma unroll
        for (int m = 0; m < 4; m++)
            #pragma unroll
            for (int j = 0; j < 4; j++) {
                ps0[m][j] += __shfl_xor(ps0[m][j], off);
                ps1[m][j] += __shfl_xor(ps1[m][j], off);
            }
    if (frow == 0) {
        #pragma unroll
        for (int m = 0; m < 4; m++)
            #pragma unroll
            for (int j = 0; j < 4; j++) {
                int row = (m << 4) + (fk << 2) + j;
                red0[w][row] = ps0[m][j];
                red1[w][row] = ps1[m][j];
            }
    }

    #pragma unroll
    for (int n = 0; n < 4; n++) {
        embp[n] += __shfl_xor(embp[n], 16);
        embp[n] += __shfl_xor(embp[n], 32);
    }
    if (l < 16) {
        #pragma unroll
        for (int n = 0; n < 4; n++)
            atomicAdd(emb + (size_t)batch * 256 + (w << 6) + (n << 4) + l, embp[n]);
    }

    __syncthreads();
    if (t < BMV) {
        float v0 = red0[0][t] + red0[1][t] + red0[2][t] + red0[3][t] + b2[0];
        float v1 = red1[0][t] + red1[1][t] + red1[2][t] + red1[3][t] + b2[1];
        Dreg[row0 + t] = v0;    // raw e2 ch0 (symmetrized in recon)
        Wreg[row0 + t] = v1;
    }
}

// ---------------------------------------------------------------------------
// Kernel 2: fused symmetrize+softplus (writes D/W outputs) + register MDS
// recon. 1 block = 1 wave = 1 batch; lane i<21 owns row i.
// ---------------------------------------------------------------------------
__global__ __launch_bounds__(64) void symrecon_kernel(
    float* __restrict__ Dreg, float* __restrict__ Wreg,
    const float* __restrict__ un, const float* __restrict__ xn,
    float* __restrict__ Xo)
{
    const int b = blockIdx.x, l = threadIdx.x;
    __shared__ float R0[NN], R1[NN];

    float* Db = Dreg + (size_t)b * NN;
    float* Wb = Wreg + (size_t)b * NN;
    for (int idx = l; idx < NN; idx += 64) { R0[idx] = Db[idx]; R1[idx] = Wb[idx]; }
    __syncthreads();

    const bool act = (l < NMAX);
    const int li = act ? l : 0;
    float Drow[NMAX], Wrow[NMAX];
    float rs = 0.f;
    #pragma unroll
    for (int q = 0; q < NMAX; q++) {
        float rd = R0[li * NMAX + q] + R0[q * NMAX + li];
        float rw = R1[li * NMAX + q] + R1[q * NMAX + li];
        float d = (q == li) ? 0.f : softplus_f(rd);
        float wv = softplus_f(rw);
        Drow[q] = act ? d : 0.f;
        Wrow[q] = act ? wv : 0.f;
        rs += Drow[q];
    }
    if (act) {
        #pragma unroll
        for (int q = 0; q < NMAX; q++) {
            Db[l * NMAX + q] = Drow[q];
            Wb[l * NMAX + q] = Wrow[q];
        }
    }

    // double-centering -> A rows in registers
    float tot = rs;
    #pragma unroll
    for (int m = 1; m < 64; m <<= 1) tot += __shfl_xor(tot, m);
    const float mean = tot * (1.f / (float)NN);
    const float rsn = rs * (1.f / (float)NMAX);
    float Arow[NMAX];
    #pragma unroll
    for (int q = 0; q < NMAX; q++) {
        float rsq = __shfl(rsn, q);
        float v = -0.5f * (Drow[q] - rsn - rsq + mean);
        Arow[q] = act ? v : 0.f;
    }

    // deflated power iteration: k=3 eigvecs, 10 steps each
    float xr[3] = {0.f, 0.f, 0.f};
    #pragma unroll
    for (int e = 0; e < 3; e++) {
        float u = act ? un[(size_t)b * 63 + e * NMAX + l] : 0.f;
        for (int s = 0; s < 10; s++) {
            float n2 = u * u;
            #pragma unroll
            for (int m = 1; m < 64; m <<= 1) n2 += __shfl_xor(n2, m);
            u *= 1.f / fmaxf(sqrtf(n2), 1e-3f);
            float a = 0.f;
            #pragma unroll
            for (int q = 0; q < NMAX; q++) a = fmaf(Arow[q], __shfl(u, q), a);
            u = act ? a : 0.f;
        }
        float e2 = u * u;
        #pragma unroll
        for (int m = 1; m < 64; m <<= 1) e2 += __shfl_xor(e2, m);
        u *= 1.f / sqrtf(sqrtf(e2 + 0.01f));
        xr[e] = u;
        #pragma unroll
        for (int q = 0; q < NMAX; q++) Arow[q] = fmaf(-u, __shfl(u, q), Arow[q]);
    }
    float x = xr[0], y = xr[1], z = xr[2];
    if (act) {
        x += xn[(size_t)b * 63 + l * 3 + 0];
        y += xn[(size_t)b * 63 + l * 3 + 1];
        z += xn[(size_t)b * 63 + l * 3 + 2];
    }

    // 100 clipped gradient-descent steps (registers + shuffles only)
    for (int tstep = 0; tstep < 100; tstep++) {
        float gx = 0.f, gy = 0.f, gz = 0.f;
        #pragma unroll
        for (int q = 0; q < NMAX; q++) {
            float dx = x - __shfl(x, q);
            float dy = y - __shfl(y, q);
            float dz = z - __shfl(z, q);
            float s = fmaf(dx, dx, fmaf(dy, dy, fmaf(dz, dz, 0.01f)));
            float cm = Wrow[q] * (Drow[q] - s);
            gx = fmaf(cm, dx, gx);
            gy = fmaf(cm, dy, gy);
            gz = fmaf(cm, dz, gz);
        }
        float d0 = 0.8f * gx, d1 = 0.8f * gy, d2 = 0.8f * gz;
        float speed = sqrtf(fmaf(d0, d0, fmaf(d1, d1, fmaf(d2, d2, 1e-3f))));
        float alpha = 0.1f + 4.9f * (100.f - (float)tstep) * 0.01f;
        float scale = alpha * tanhf(speed / alpha) / speed;
        x = fmaf(d0, scale, x);
        y = fmaf(d1, scale, y);
        z = fmaf(d2, scale, z);
    }
    if (act) {
        Xo[(size_t)b * 63 + l * 3 + 0] = x;
        Xo[(size_t)b * 63 + l * 3 + 1] = y;
        Xo[(size_t)b * 63 + l * 3 + 2] = z;
    }
}

// ---------------------------------------------------------------------------
extern "C" void kernel_launch(void* const* d_in, const int* in_sizes, int n_in,
                              void* d_out, int out_size, void* d_ws, size_t ws_size,
                              hipStream_t stream) {
    const float* gnn = (const float*)d_in[0];
    const float* W1  = (const float*)d_in[1];
    const float* b1  = (const float*)d_in[2];
    const float* W2  = (const float*)d_in[3];
    const float* b2  = (const float*)d_in[4];
    const float* un  = (const float*)d_in[5];
    const float* xn  = (const float*)d_in[6];

    float* out  = (float*)d_out;
    float* Dreg = out;                                  // [1024*441]
    float* Wreg = out + (size_t)TOT_ROWS;               // [1024*441]
    float* emb  = out + (size_t)2 * TOT_ROWS;           // [1024*256]
    float* Xo   = out + (size_t)2 * TOT_ROWS + B_SZ*256;// [1024*63]

    short* B0p = (short*)d_ws;                          // 65536 bf16 (128KB)

    pack_w1<<<dim3(256), dim3(256), 0, stream>>>(W1, B0p);
    hipMemsetAsync(emb, 0, (size_t)B_SZ * 256 * sizeof(float), stream);

    fused_mlp_bf16<<<dim3(B_SZ * TILES_PER_BATCH), dim3(256), 0, stream>>>(
        gnn, B0p, b1, W2, b2, Dreg, Wreg, emb);

    symrecon_kernel<<<dim3(B_SZ), dim3(64), 0, stream>>>(Dreg, Wreg, un, xn, Xo);
}